// Round 13
// baseline (190.599 us; speedup 1.0000x reference)
//
#include <hip/hip_runtime.h>

#define D 128
#define BKT_SHIFT 9                 // 512 nodes per bucket
#define BKT_NODES 512
#define NBK 128                     // max buckets supported
#define CHUNK 2048
#define CAP 12288                   // bucket capacity (mean ~8163, sigma ~90)

typedef short short8 __attribute__((ext_vector_type(8)));
typedef float f32x4  __attribute__((ext_vector_type(4)));

__device__ __forceinline__ unsigned short f2bf(float f) {
    unsigned int u = __builtin_bit_cast(unsigned int, f);
    u += 0x7FFFu + ((u >> 16) & 1u);           // round-to-nearest-even
    return (unsigned short)(u >> 16);
}
__device__ __forceinline__ float bflo(unsigned int u) {
    return __builtin_bit_cast(float, u << 16);
}
__device__ __forceinline__ float bfhi(unsigned int u) {
    return __builtin_bit_cast(float, u & 0xFFFF0000u);
}

// ------- prep + bucketing fused (independent block ranges) -----------------
__global__ __launch_bounds__(256) void prep_bucket(
    const float* __restrict__ h, unsigned short* __restrict__ hbf, int n8,
    int hblocks,
    const float* __restrict__ W1, const float* __restrict__ W2,
    unsigned short* __restrict__ wf1, unsigned short* __restrict__ wf2,
    const int* __restrict__ esrc, const int* __restrict__ edst,
    int* __restrict__ cursor, int* __restrict__ adj_st, int n_edges)
{
    const int bid = blockIdx.x;
    const int tid = threadIdx.x;
    if (bid < hblocks) {
        const int t = bid * 256 + tid;
        if (t >= n8) return;
        const float4 a = reinterpret_cast<const float4*>(h)[t * 2];
        const float4 b = reinterpret_cast<const float4*>(h)[t * 2 + 1];
        union { short8 s; unsigned short u[8]; } pk;
        pk.u[0]=f2bf(a.x); pk.u[1]=f2bf(a.y); pk.u[2]=f2bf(a.z); pk.u[3]=f2bf(a.w);
        pk.u[4]=f2bf(b.x); pk.u[5]=f2bf(b.y); pk.u[6]=f2bf(b.z); pk.u[7]=f2bf(b.w);
        reinterpret_cast<short8*>(hbf)[t] = pk.s;
    } else if (bid < hblocks + 32) {
        const int t = (bid - hblocks) * 256 + tid;      // 0..8191
        const int which = t >> 12;
        const int u = t & 4095;
        const float* W = which ? W2 : W1;
        unsigned short* wf = which ? wf2 : wf1;
        const int lane = u & 63;
        const int frag = u >> 6;                        // ct*8 + kc
        const int ctb  = frag >> 3;
        const int kc   = frag & 7;
        const int col  = ctb * 16 + (lane & 15);
        const int k0   = kc * 32 + (lane >> 4) * 8;
        unsigned short o[8];
        #pragma unroll
        for (int j = 0; j < 8; ++j) o[j] = f2bf(W[(size_t)(k0 + j) * D + col]);
        #pragma unroll
        for (int j = 0; j < 8; ++j) wf[(size_t)u * 8 + j] = o[j];
    } else {
        __shared__ int lcnt[NBK], lbase[NBK];
        const int base = (bid - hblocks - 32) * CHUNK;
        if (tid < NBK) lcnt[tid] = 0;
        __syncthreads();
        int d[8], s[8], loc[8];
        #pragma unroll
        for (int k = 0; k < 8; ++k) {
            const int i = base + k * 256 + tid;
            if (i < n_edges) {
                d[k] = edst[i]; s[k] = esrc[i];
                loc[k] = atomicAdd(&lcnt[d[k] >> BKT_SHIFT], 1);
            }
        }
        __syncthreads();
        if (tid < NBK)
            lbase[tid] = tid * CAP +
                (lcnt[tid] ? atomicAdd(&cursor[tid], lcnt[tid]) : 0);
        __syncthreads();
        #pragma unroll
        for (int k = 0; k < 8; ++k) {
            const int i = base + k * 256 + tid;
            if (i < n_edges) {
                const int b = d[k] >> BKT_SHIFT;
                adj_st[lbase[b] + loc[k]] = (int)(
                    ((unsigned int)(d[k] & (BKT_NODES - 1)) << 16) |
                    (unsigned int)s[k]);
            }
        }
    }
}

// ------- per-bucket finalize via LDS: row_start + deg + adj (in-place) -----
__global__ __launch_bounds__(256) void bucket_fill(
    const int* __restrict__ cursor, int* __restrict__ adj_st,
    int* __restrict__ row_start, int* __restrict__ deg, int n_nodes)
{
    __shared__ unsigned int lbuf[CAP];                  // 48 KB
    __shared__ int cnt[BKT_NODES], pref[BKT_NODES], cur[BKT_NODES];
    __shared__ int wsum[4];
    const int b   = blockIdx.x;
    const int tid = threadIdx.x;
    const int nb  = min(cursor[b], CAP);
    const int s0  = b * CAP;

    for (int i = tid; i < nb; i += 256) lbuf[i] = (unsigned int)adj_st[s0 + i];
    for (int i = tid; i < BKT_NODES; i += 256) cnt[i] = 0;
    __syncthreads();
    for (int i = tid; i < nb; i += 256)
        atomicAdd(&cnt[lbuf[i] >> 16], 1);
    __syncthreads();

    const int lane = tid & 63, w = tid >> 6;
    const int v0 = cnt[2 * tid], v1 = cnt[2 * tid + 1];
    const int sv = v0 + v1;
    int incl = sv;
    #pragma unroll
    for (int off = 1; off < 64; off <<= 1) {
        int t = __shfl_up(incl, off, 64);
        if (lane >= off) incl += t;
    }
    if (lane == 63) wsum[w] = incl;
    __syncthreads();
    int wp = 0;
    #pragma unroll
    for (int k = 0; k < 4; ++k) if (k < w) wp += wsum[k];
    const int ex = wp + incl - sv;
    pref[2 * tid] = ex;           cur[2 * tid] = 0;
    pref[2 * tid + 1] = ex + v0;  cur[2 * tid + 1] = 0;
    __syncthreads();

    for (int r = tid; r < BKT_NODES; r += 256) {
        const int node = b * BKT_NODES + r;
        if (node < n_nodes) { row_start[node] = s0 + pref[r]; deg[node] = cnt[r]; }
    }

    for (int i = tid; i < nb; i += 256) {
        const unsigned int p = lbuf[i];
        const int r = p >> 16;
        adj_st[s0 + pref[r] + atomicAdd(&cur[r], 1)] = (int)(p & 0xFFFFu);
    }
}

// ------- gather-mean for one node, one wave; returns packed bf16x2 ---------
template<bool SORT>
__device__ __forceinline__ unsigned int gather_mean(
    const unsigned int* __restrict__ h2, int* __restrict__ adj,
    int s0, int d, int lane)
{
    float ax0=0.f, ay0=0.f, ax1=0.f, ay1=0.f, ax2=0.f, ay2=0.f, ax3=0.f, ay3=0.f;
    float ax4=0.f, ay4=0.f, ax5=0.f, ay5=0.f, ax6=0.f, ay6=0.f, ax7=0.f, ay7=0.f;

    if (SORT && d <= 64) {
        int v = (lane < d) ? adj[s0 + lane] : 0x7FFFFFFF;
        if (d > 1) {
            #pragma unroll
            for (int k = 2; k <= 64; k <<= 1) {
                #pragma unroll
                for (int j = k >> 1; j >= 1; j >>= 1) {
                    const int p = __shfl_xor(v, j, 64);
                    const bool keepMin = (((lane & k) == 0) == ((lane & j) == 0));
                    v = keepMin ? (v < p ? v : p) : (v > p ? v : p);
                }
            }
            if (lane < d) adj[s0 + lane] = v;   // sorted row for layer 2
        }
        int p = 0;
        for (; p + 7 < d; p += 8) {
            const int i0 = __shfl(v, p),     i1 = __shfl(v, p + 1);
            const int i2 = __shfl(v, p + 2), i3 = __shfl(v, p + 3);
            const int i4 = __shfl(v, p + 4), i5 = __shfl(v, p + 5);
            const int i6 = __shfl(v, p + 6), i7 = __shfl(v, p + 7);
            const unsigned int w0 = h2[(size_t)i0 * 64 + lane];
            const unsigned int w1 = h2[(size_t)i1 * 64 + lane];
            const unsigned int w2 = h2[(size_t)i2 * 64 + lane];
            const unsigned int w3 = h2[(size_t)i3 * 64 + lane];
            const unsigned int w4 = h2[(size_t)i4 * 64 + lane];
            const unsigned int w5 = h2[(size_t)i5 * 64 + lane];
            const unsigned int w6 = h2[(size_t)i6 * 64 + lane];
            const unsigned int w7 = h2[(size_t)i7 * 64 + lane];
            ax0 += bflo(w0); ay0 += bfhi(w0); ax1 += bflo(w1); ay1 += bfhi(w1);
            ax2 += bflo(w2); ay2 += bfhi(w2); ax3 += bflo(w3); ay3 += bfhi(w3);
            ax4 += bflo(w4); ay4 += bfhi(w4); ax5 += bflo(w5); ay5 += bfhi(w5);
            ax6 += bflo(w6); ay6 += bfhi(w6); ax7 += bflo(w7); ay7 += bfhi(w7);
        }
        for (; p < d; ++p) {
            const int i0 = __shfl(v, p);
            const unsigned int a = h2[(size_t)i0 * 64 + lane];
            ax0 += bflo(a); ay0 += bfhi(a);
        }
    } else {
        int p = 0;
        for (; p + 7 < d; p += 8) {
            const int i0 = adj[s0+p],   i1 = adj[s0+p+1], i2 = adj[s0+p+2], i3 = adj[s0+p+3];
            const int i4 = adj[s0+p+4], i5 = adj[s0+p+5], i6 = adj[s0+p+6], i7 = adj[s0+p+7];
            const unsigned int w0 = h2[(size_t)i0 * 64 + lane];
            const unsigned int w1 = h2[(size_t)i1 * 64 + lane];
            const unsigned int w2 = h2[(size_t)i2 * 64 + lane];
            const unsigned int w3 = h2[(size_t)i3 * 64 + lane];
            const unsigned int w4 = h2[(size_t)i4 * 64 + lane];
            const unsigned int w5 = h2[(size_t)i5 * 64 + lane];
            const unsigned int w6 = h2[(size_t)i6 * 64 + lane];
            const unsigned int w7 = h2[(size_t)i7 * 64 + lane];
            ax0 += bflo(w0); ay0 += bfhi(w0); ax1 += bflo(w1); ay1 += bfhi(w1);
            ax2 += bflo(w2); ay2 += bfhi(w2); ax3 += bflo(w3); ay3 += bfhi(w3);
            ax4 += bflo(w4); ay4 += bfhi(w4); ax5 += bflo(w5); ay5 += bfhi(w5);
            ax6 += bflo(w6); ay6 += bfhi(w6); ax7 += bflo(w7); ay7 += bfhi(w7);
        }
        for (; p < d; ++p) {
            const unsigned int a = h2[(size_t)adj[s0 + p] * 64 + lane];
            ax0 += bflo(a); ay0 += bfhi(a);
        }
    }
    const float inv = 1.0f / (float)(d > 0 ? d : 1);
    const float sx = (((ax0 + ax1) + (ax2 + ax3)) + ((ax4 + ax5) + (ax6 + ax7))) * inv;
    const float sy = (((ay0 + ay1) + (ay2 + ay3)) + ((ay4 + ay5) + (ay6 + ay7))) * inv;
    return (unsigned int)f2bf(sx) | ((unsigned int)f2bf(sy) << 16);
}

// -------- fused layer: gather-mean -> LDS A-tile -> MFMA -> relu store -----
// 256 thr = 4 waves; block = 64 nodes; wave w gathers nodes [w*16, w*16+16).
template<bool SORT, bool OUT_BF16>
__global__ __launch_bounds__(256) void fused_layer(
    const unsigned short* __restrict__ hbf, int* __restrict__ adj,
    const int* __restrict__ row_start, const int* __restrict__ deg,
    const unsigned short* __restrict__ wfrag, const float* __restrict__ bias,
    float* __restrict__ outf, unsigned short* __restrict__ outbf, int n_nodes)
{
    __shared__ unsigned short sA[64 * 256];   // 32 KB
    unsigned int* sA32 = reinterpret_cast<unsigned int*>(sA);
    const int tid  = threadIdx.x;
    const int wv   = tid >> 6;
    const int lane = tid & 63;
    const int base = blockIdx.x * 64;
    const unsigned int* h2 = reinterpret_cast<const unsigned int*>(hbf);

    // ---- gather phase: own row + neighbor mean, written swizzled to LDS ---
    const int cco = lane >> 2;                // own-chunk 0..15
    const int sub = lane & 3;                 // u32 within 16B chunk
    for (int i = 0; i < 16; ++i) {
        const int r    = wv * 16 + i;
        const int node = base + r;
        unsigned int own = 0, msg = 0;
        if (node < n_nodes) {
            own = h2[(size_t)node * 64 + lane];
            msg = gather_mean<SORT>(h2, adj, row_start[node], deg[node], lane);
        }
        sA32[r * 128 + (((cco     ) ^ (r & 7)) << 2) + sub] = own;
        sA32[r * 128 + (((cco + 16) ^ (r & 7)) << 2) + sub] = msg;
    }
    __syncthreads();

    // ---- MFMA phase ----
    const int lrow = wv * 16 + (lane & 15);
    const int lgrp = lane >> 4;
    short8 a[8];
    #pragma unroll
    for (int kc = 0; kc < 8; ++kc) {
        const int chunk = kc * 4 + lgrp;
        a[kc] = *reinterpret_cast<const short8*>(
            &sA[lrow * 256 + ((chunk ^ (lrow & 7)) * 8)]);
    }

    const short8* wf = reinterpret_cast<const short8*>(wfrag);
    f32x4 acc[8];
    #pragma unroll
    for (int ct = 0; ct < 8; ++ct) {
        const float bb = bias[ct * 16 + (lane & 15)];
        acc[ct] = (f32x4){bb, bb, bb, bb};
    }
    #pragma unroll
    for (int ct = 0; ct < 8; ++ct) {
        #pragma unroll
        for (int kc = 0; kc < 8; ++kc) {
            const short8 b = wf[(ct * 8 + kc) * 64 + lane];
            acc[ct] = __builtin_amdgcn_mfma_f32_16x16x32_bf16(a[kc], b, acc[ct], 0, 0, 0);
        }
    }

    #pragma unroll
    for (int ct = 0; ct < 8; ++ct) {
        const int col = ct * 16 + (lane & 15);
        #pragma unroll
        for (int rg = 0; rg < 4; ++rg) {
            const int node = base + wv * 16 + lgrp * 4 + rg;
            if (node < n_nodes) {
                const float r = fmaxf(acc[ct][rg], 0.f);
                if (OUT_BF16) outbf[(size_t)node * D + col] = f2bf(r);
                else          outf [(size_t)node * D + col] = r;
            }
        }
    }
}

// ---------------------------------------------------------------------------
extern "C" void kernel_launch(void* const* d_in, const int* in_sizes, int n_in,
                              void* d_out, int out_size, void* d_ws, size_t ws_size,
                              hipStream_t stream)
{
    const float* h    = (const float*)d_in[0];
    const int*   esrc = (const int*)  d_in[1];
    const int*   edst = (const int*)  d_in[2];
    const float* W1   = (const float*)d_in[3];
    const float* b1   = (const float*)d_in[4];
    const float* W2   = (const float*)d_in[5];
    const float* b2   = (const float*)d_in[6];
    float* out = (float*)d_out;

    const int n_nodes = in_sizes[0] / D;
    const int n_edges = in_sizes[1];
    const int nbuck   = (n_nodes + BKT_NODES - 1) >> BKT_SHIFT;

    // workspace layout
    unsigned short* hbf   = (unsigned short*)d_ws;                 // [N][D]
    unsigned short* h1bf  = hbf  + (size_t)n_nodes * D;            // [N][D]
    unsigned short* wf1   = h1bf + (size_t)n_nodes * D;            // [32768]
    unsigned short* wf2   = wf1 + 32768;                           // [32768]
    int* adj_st           = (int*)(wf2 + 32768);                   // [nbuck*CAP]
    int* row_start        = adj_st + (size_t)nbuck * CAP;          // [N]
    int* deg              = row_start + n_nodes;                   // [N]
    int* cursor           = deg + n_nodes;                         // [NBK]

    const int nchunks = (n_edges + CHUNK - 1) / CHUNK;
    const int layer_blocks = (n_nodes + 63) / 64;
    const int n8 = n_nodes * D / 8;
    const int hblocks = (n8 + 255) / 256;

    // ---- precompute: conversions + single-pass bucketing (shared) ----
    (void)hipMemsetAsync(cursor, 0, NBK * sizeof(int), stream);
    prep_bucket<<<hblocks + 32 + nchunks, 256, 0, stream>>>(
        h, hbf, n8, hblocks, W1, W2, wf1, wf2, esrc, edst, cursor, adj_st, n_edges);
    bucket_fill<<<nbuck, 256, 0, stream>>>(cursor, adj_st, row_start, deg, n_nodes);

    // ---- layer 1: hbf -> h1bf (sorts rows in-flight, writes back) ----
    fused_layer<true, true><<<layer_blocks, 256, 0, stream>>>(
        hbf, adj_st, row_start, deg, wf1, b1, nullptr, h1bf, n_nodes);

    // ---- layer 2: h1bf -> out (f32) ----
    fused_layer<false, false><<<layer_blocks, 256, 0, stream>>>(
        h1bf, adj_st, row_start, deg, wf2, b2, out, nullptr, n_nodes);
}

// Round 14
// 140.643 us; speedup vs baseline: 1.3552x; 1.3552x over previous
//
#include <hip/hip_runtime.h>

#define D 128
#define BKT_SHIFT 9                 // 512 nodes per bucket
#define BKT_NODES 512
#define NBK 128                     // max buckets supported
#define CHUNK 2048
#define CAP 12288                   // bucket capacity (mean ~8163, sigma ~90)

typedef short short8 __attribute__((ext_vector_type(8)));
typedef float f32x4  __attribute__((ext_vector_type(4)));

__device__ __forceinline__ unsigned short f2bf(float f) {
    unsigned int u = __builtin_bit_cast(unsigned int, f);
    u += 0x7FFFu + ((u >> 16) & 1u);           // round-to-nearest-even
    return (unsigned short)(u >> 16);
}
__device__ __forceinline__ float bflo(unsigned int u) {
    return __builtin_bit_cast(float, u << 16);
}
__device__ __forceinline__ float bfhi(unsigned int u) {
    return __builtin_bit_cast(float, u & 0xFFFF0000u);
}

// ------- prep + bucketing fused (independent block ranges) -----------------
__global__ __launch_bounds__(256) void prep_bucket(
    const float* __restrict__ h, unsigned short* __restrict__ hbf, int n8,
    int hblocks,
    const float* __restrict__ W1, const float* __restrict__ W2,
    unsigned short* __restrict__ wf1, unsigned short* __restrict__ wf2,
    const int* __restrict__ esrc, const int* __restrict__ edst,
    int* __restrict__ cursor, int* __restrict__ adj_st, int n_edges)
{
    const int bid = blockIdx.x;
    const int tid = threadIdx.x;
    if (bid < hblocks) {
        const int t = bid * 256 + tid;
        if (t >= n8) return;
        const float4 a = reinterpret_cast<const float4*>(h)[t * 2];
        const float4 b = reinterpret_cast<const float4*>(h)[t * 2 + 1];
        union { short8 s; unsigned short u[8]; } pk;
        pk.u[0]=f2bf(a.x); pk.u[1]=f2bf(a.y); pk.u[2]=f2bf(a.z); pk.u[3]=f2bf(a.w);
        pk.u[4]=f2bf(b.x); pk.u[5]=f2bf(b.y); pk.u[6]=f2bf(b.z); pk.u[7]=f2bf(b.w);
        reinterpret_cast<short8*>(hbf)[t] = pk.s;
    } else if (bid < hblocks + 32) {
        const int t = (bid - hblocks) * 256 + tid;      // 0..8191
        const int which = t >> 12;
        const int u = t & 4095;
        const float* W = which ? W2 : W1;
        unsigned short* wf = which ? wf2 : wf1;
        const int lane = u & 63;
        const int frag = u >> 6;                        // ct*8 + kc
        const int ctb  = frag >> 3;
        const int kc   = frag & 7;
        const int col  = ctb * 16 + (lane & 15);
        const int k0   = kc * 32 + (lane >> 4) * 8;
        unsigned short o[8];
        #pragma unroll
        for (int j = 0; j < 8; ++j) o[j] = f2bf(W[(size_t)(k0 + j) * D + col]);
        #pragma unroll
        for (int j = 0; j < 8; ++j) wf[(size_t)u * 8 + j] = o[j];
    } else {
        __shared__ int lcnt[NBK], lbase[NBK];
        const int base = (bid - hblocks - 32) * CHUNK;
        if (tid < NBK) lcnt[tid] = 0;
        __syncthreads();
        int d[8], s[8], loc[8];
        #pragma unroll
        for (int k = 0; k < 8; ++k) {
            const int i = base + k * 256 + tid;
            if (i < n_edges) {
                d[k] = edst[i]; s[k] = esrc[i];
                loc[k] = atomicAdd(&lcnt[d[k] >> BKT_SHIFT], 1);
            }
        }
        __syncthreads();
        if (tid < NBK)
            lbase[tid] = tid * CAP +
                (lcnt[tid] ? atomicAdd(&cursor[tid], lcnt[tid]) : 0);
        __syncthreads();
        #pragma unroll
        for (int k = 0; k < 8; ++k) {
            const int i = base + k * 256 + tid;
            if (i < n_edges) {
                const int b = d[k] >> BKT_SHIFT;
                adj_st[lbase[b] + loc[k]] = (int)(
                    ((unsigned int)(d[k] & (BKT_NODES - 1)) << 16) |
                    (unsigned int)s[k]);
            }
        }
    }
}

// ------- per-bucket finalize via LDS: row_start + deg + adj (in-place) -----
__global__ __launch_bounds__(256) void bucket_fill(
    const int* __restrict__ cursor, int* __restrict__ adj_st,
    int* __restrict__ row_start, int* __restrict__ deg, int n_nodes)
{
    __shared__ unsigned int lbuf[CAP];                  // 48 KB
    __shared__ int cnt[BKT_NODES], pref[BKT_NODES], cur[BKT_NODES];
    __shared__ int wsum[4];
    const int b   = blockIdx.x;
    const int tid = threadIdx.x;
    const int nb  = min(cursor[b], CAP);
    const int s0  = b * CAP;

    for (int i = tid; i < nb; i += 256) lbuf[i] = (unsigned int)adj_st[s0 + i];
    for (int i = tid; i < BKT_NODES; i += 256) cnt[i] = 0;
    __syncthreads();
    for (int i = tid; i < nb; i += 256)
        atomicAdd(&cnt[lbuf[i] >> 16], 1);
    __syncthreads();

    const int lane = tid & 63, w = tid >> 6;
    const int v0 = cnt[2 * tid], v1 = cnt[2 * tid + 1];
    const int sv = v0 + v1;
    int incl = sv;
    #pragma unroll
    for (int off = 1; off < 64; off <<= 1) {
        int t = __shfl_up(incl, off, 64);
        if (lane >= off) incl += t;
    }
    if (lane == 63) wsum[w] = incl;
    __syncthreads();
    int wp = 0;
    #pragma unroll
    for (int k = 0; k < 4; ++k) if (k < w) wp += wsum[k];
    const int ex = wp + incl - sv;
    pref[2 * tid] = ex;           cur[2 * tid] = 0;
    pref[2 * tid + 1] = ex + v0;  cur[2 * tid + 1] = 0;
    __syncthreads();

    for (int r = tid; r < BKT_NODES; r += 256) {
        const int node = b * BKT_NODES + r;
        if (node < n_nodes) { row_start[node] = s0 + pref[r]; deg[node] = cnt[r]; }
    }

    for (int i = tid; i < nb; i += 256) {
        const unsigned int p = lbuf[i];
        const int r = p >> 16;
        adj_st[s0 + pref[r] + atomicAdd(&cur[r], 1)] = (int)(p & 0xFFFFu);
    }
}

// ------- gather L1: sort row in-reg (bitonic), write back, gather via shfl -
// 16 independent 256B row loads in flight (latency-bound -> maximize MLP).
__global__ __launch_bounds__(256) void gather_sort(
    const unsigned short* __restrict__ hbf, int* __restrict__ adj,
    const int* __restrict__ row_start, const int* __restrict__ deg,
    unsigned short* __restrict__ msgbf, int n_nodes)
{
    const int lane = threadIdx.x & 63;
    const int node = (blockIdx.x * 256 + threadIdx.x) >> 6;
    if (node >= n_nodes) return;
    const unsigned int* h2 = reinterpret_cast<const unsigned int*>(hbf);

    const int s0 = row_start[node];
    const int d  = deg[node];
    float ax0=0.f, ay0=0.f, ax1=0.f, ay1=0.f, ax2=0.f, ay2=0.f, ax3=0.f, ay3=0.f;
    float ax4=0.f, ay4=0.f, ax5=0.f, ay5=0.f, ax6=0.f, ay6=0.f, ax7=0.f, ay7=0.f;

    if (d <= 64) {
        int v = (lane < d) ? adj[s0 + lane] : 0x7FFFFFFF;
        if (d > 1) {
            #pragma unroll
            for (int k = 2; k <= 64; k <<= 1) {
                #pragma unroll
                for (int j = k >> 1; j >= 1; j >>= 1) {
                    const int p = __shfl_xor(v, j, 64);
                    const bool keepMin = (((lane & k) == 0) == ((lane & j) == 0));
                    v = keepMin ? (v < p ? v : p) : (v > p ? v : p);
                }
            }
            if (lane < d) adj[s0 + lane] = v;   // sorted row for layer 2
        }
        int p = 0;
        for (; p + 15 < d; p += 16) {          // 16 rows in flight
            const unsigned int w0  = h2[(unsigned)__shfl(v, p     ) * 64 + lane];
            const unsigned int w1  = h2[(unsigned)__shfl(v, p +  1) * 64 + lane];
            const unsigned int w2  = h2[(unsigned)__shfl(v, p +  2) * 64 + lane];
            const unsigned int w3  = h2[(unsigned)__shfl(v, p +  3) * 64 + lane];
            const unsigned int w4  = h2[(unsigned)__shfl(v, p +  4) * 64 + lane];
            const unsigned int w5  = h2[(unsigned)__shfl(v, p +  5) * 64 + lane];
            const unsigned int w6  = h2[(unsigned)__shfl(v, p +  6) * 64 + lane];
            const unsigned int w7  = h2[(unsigned)__shfl(v, p +  7) * 64 + lane];
            const unsigned int w8  = h2[(unsigned)__shfl(v, p +  8) * 64 + lane];
            const unsigned int w9  = h2[(unsigned)__shfl(v, p +  9) * 64 + lane];
            const unsigned int w10 = h2[(unsigned)__shfl(v, p + 10) * 64 + lane];
            const unsigned int w11 = h2[(unsigned)__shfl(v, p + 11) * 64 + lane];
            const unsigned int w12 = h2[(unsigned)__shfl(v, p + 12) * 64 + lane];
            const unsigned int w13 = h2[(unsigned)__shfl(v, p + 13) * 64 + lane];
            const unsigned int w14 = h2[(unsigned)__shfl(v, p + 14) * 64 + lane];
            const unsigned int w15 = h2[(unsigned)__shfl(v, p + 15) * 64 + lane];
            ax0 += bflo(w0);  ay0 += bfhi(w0);  ax1 += bflo(w1);  ay1 += bfhi(w1);
            ax2 += bflo(w2);  ay2 += bfhi(w2);  ax3 += bflo(w3);  ay3 += bfhi(w3);
            ax4 += bflo(w4);  ay4 += bfhi(w4);  ax5 += bflo(w5);  ay5 += bfhi(w5);
            ax6 += bflo(w6);  ay6 += bfhi(w6);  ax7 += bflo(w7);  ay7 += bfhi(w7);
            ax0 += bflo(w8);  ay0 += bfhi(w8);  ax1 += bflo(w9);  ay1 += bfhi(w9);
            ax2 += bflo(w10); ay2 += bfhi(w10); ax3 += bflo(w11); ay3 += bfhi(w11);
            ax4 += bflo(w12); ay4 += bfhi(w12); ax5 += bflo(w13); ay5 += bfhi(w13);
            ax6 += bflo(w14); ay6 += bfhi(w14); ax7 += bflo(w15); ay7 += bfhi(w15);
        }
        for (; p + 7 < d; p += 8) {
            const unsigned int w0 = h2[(unsigned)__shfl(v, p    ) * 64 + lane];
            const unsigned int w1 = h2[(unsigned)__shfl(v, p + 1) * 64 + lane];
            const unsigned int w2 = h2[(unsigned)__shfl(v, p + 2) * 64 + lane];
            const unsigned int w3 = h2[(unsigned)__shfl(v, p + 3) * 64 + lane];
            const unsigned int w4 = h2[(unsigned)__shfl(v, p + 4) * 64 + lane];
            const unsigned int w5 = h2[(unsigned)__shfl(v, p + 5) * 64 + lane];
            const unsigned int w6 = h2[(unsigned)__shfl(v, p + 6) * 64 + lane];
            const unsigned int w7 = h2[(unsigned)__shfl(v, p + 7) * 64 + lane];
            ax0 += bflo(w0); ay0 += bfhi(w0); ax1 += bflo(w1); ay1 += bfhi(w1);
            ax2 += bflo(w2); ay2 += bfhi(w2); ax3 += bflo(w3); ay3 += bfhi(w3);
            ax4 += bflo(w4); ay4 += bfhi(w4); ax5 += bflo(w5); ay5 += bfhi(w5);
            ax6 += bflo(w6); ay6 += bfhi(w6); ax7 += bflo(w7); ay7 += bfhi(w7);
        }
        for (; p < d; ++p) {
            const unsigned int a = h2[(unsigned)__shfl(v, p) * 64 + lane];
            ax0 += bflo(a); ay0 += bfhi(a);
        }
    } else {
        int p = 0;
        for (; p + 7 < d; p += 8) {
            const int i0 = adj[s0+p],   i1 = adj[s0+p+1], i2 = adj[s0+p+2], i3 = adj[s0+p+3];
            const int i4 = adj[s0+p+4], i5 = adj[s0+p+5], i6 = adj[s0+p+6], i7 = adj[s0+p+7];
            const unsigned int w0 = h2[(unsigned)i0 * 64 + lane];
            const unsigned int w1 = h2[(unsigned)i1 * 64 + lane];
            const unsigned int w2 = h2[(unsigned)i2 * 64 + lane];
            const unsigned int w3 = h2[(unsigned)i3 * 64 + lane];
            const unsigned int w4 = h2[(unsigned)i4 * 64 + lane];
            const unsigned int w5 = h2[(unsigned)i5 * 64 + lane];
            const unsigned int w6 = h2[(unsigned)i6 * 64 + lane];
            const unsigned int w7 = h2[(unsigned)i7 * 64 + lane];
            ax0 += bflo(w0); ay0 += bfhi(w0); ax1 += bflo(w1); ay1 += bfhi(w1);
            ax2 += bflo(w2); ay2 += bfhi(w2); ax3 += bflo(w3); ay3 += bfhi(w3);
            ax4 += bflo(w4); ay4 += bfhi(w4); ax5 += bflo(w5); ay5 += bfhi(w5);
            ax6 += bflo(w6); ay6 += bfhi(w6); ax7 += bflo(w7); ay7 += bfhi(w7);
        }
        for (; p < d; ++p) {
            const unsigned int a = h2[(unsigned)adj[s0 + p] * 64 + lane];
            ax0 += bflo(a); ay0 += bfhi(a);
        }
    }
    const float inv = 1.0f / (float)(d > 0 ? d : 1);
    const float sx = (((ax0 + ax1) + (ax2 + ax3)) + ((ax4 + ax5) + (ax6 + ax7))) * inv;
    const float sy = (((ay0 + ay1) + (ay2 + ay3)) + ((ay4 + ay5) + (ay6 + ay7))) * inv;
    const unsigned int o = (unsigned int)f2bf(sx) | ((unsigned int)f2bf(sy) << 16);
    reinterpret_cast<unsigned int*>(msgbf)[(size_t)node * 64 + lane] = o;
}

// ------- gather L2: rows already sorted; 16 rows in flight -----------------
__global__ __launch_bounds__(256) void gather_kernel(
    const unsigned short* __restrict__ hbf, const int* __restrict__ adj,
    const int* __restrict__ row_start, const int* __restrict__ deg,
    unsigned short* __restrict__ msgbf, int n_nodes)
{
    const int lane = threadIdx.x & 63;
    const int node = (blockIdx.x * 256 + threadIdx.x) >> 6;
    if (node >= n_nodes) return;
    const unsigned int* h2 = reinterpret_cast<const unsigned int*>(hbf);

    const int s0 = row_start[node];
    const int d  = deg[node];
    const int s1 = s0 + d;
    float ax0=0.f, ay0=0.f, ax1=0.f, ay1=0.f, ax2=0.f, ay2=0.f, ax3=0.f, ay3=0.f;
    float ax4=0.f, ay4=0.f, ax5=0.f, ay5=0.f, ax6=0.f, ay6=0.f, ax7=0.f, ay7=0.f;
    int p = s0;
    for (; p + 15 < s1; p += 16) {             // 16 rows in flight
        const unsigned int w0  = h2[(unsigned)adj[p     ] * 64 + lane];
        const unsigned int w1  = h2[(unsigned)adj[p +  1] * 64 + lane];
        const unsigned int w2  = h2[(unsigned)adj[p +  2] * 64 + lane];
        const unsigned int w3  = h2[(unsigned)adj[p +  3] * 64 + lane];
        const unsigned int w4  = h2[(unsigned)adj[p +  4] * 64 + lane];
        const unsigned int w5  = h2[(unsigned)adj[p +  5] * 64 + lane];
        const unsigned int w6  = h2[(unsigned)adj[p +  6] * 64 + lane];
        const unsigned int w7  = h2[(unsigned)adj[p +  7] * 64 + lane];
        const unsigned int w8  = h2[(unsigned)adj[p +  8] * 64 + lane];
        const unsigned int w9  = h2[(unsigned)adj[p +  9] * 64 + lane];
        const unsigned int w10 = h2[(unsigned)adj[p + 10] * 64 + lane];
        const unsigned int w11 = h2[(unsigned)adj[p + 11] * 64 + lane];
        const unsigned int w12 = h2[(unsigned)adj[p + 12] * 64 + lane];
        const unsigned int w13 = h2[(unsigned)adj[p + 13] * 64 + lane];
        const unsigned int w14 = h2[(unsigned)adj[p + 14] * 64 + lane];
        const unsigned int w15 = h2[(unsigned)adj[p + 15] * 64 + lane];
        ax0 += bflo(w0);  ay0 += bfhi(w0);  ax1 += bflo(w1);  ay1 += bfhi(w1);
        ax2 += bflo(w2);  ay2 += bfhi(w2);  ax3 += bflo(w3);  ay3 += bfhi(w3);
        ax4 += bflo(w4);  ay4 += bfhi(w4);  ax5 += bflo(w5);  ay5 += bfhi(w5);
        ax6 += bflo(w6);  ay6 += bfhi(w6);  ax7 += bflo(w7);  ay7 += bfhi(w7);
        ax0 += bflo(w8);  ay0 += bfhi(w8);  ax1 += bflo(w9);  ay1 += bfhi(w9);
        ax2 += bflo(w10); ay2 += bfhi(w10); ax3 += bflo(w11); ay3 += bfhi(w11);
        ax4 += bflo(w12); ay4 += bfhi(w12); ax5 += bflo(w13); ay5 += bfhi(w13);
        ax6 += bflo(w14); ay6 += bfhi(w14); ax7 += bflo(w15); ay7 += bfhi(w15);
    }
    for (; p + 3 < s1; p += 4) {
        const int i0 = adj[p], i1 = adj[p + 1], i2 = adj[p + 2], i3 = adj[p + 3];
        const unsigned int v0 = h2[(unsigned)i0 * 64 + lane];
        const unsigned int v1 = h2[(unsigned)i1 * 64 + lane];
        const unsigned int v2 = h2[(unsigned)i2 * 64 + lane];
        const unsigned int v3 = h2[(unsigned)i3 * 64 + lane];
        ax0 += bflo(v0); ay0 += bfhi(v0); ax1 += bflo(v1); ay1 += bfhi(v1);
        ax2 += bflo(v2); ay2 += bfhi(v2); ax3 += bflo(v3); ay3 += bfhi(v3);
    }
    for (; p < s1; ++p) {
        const unsigned int a = h2[(unsigned)adj[p] * 64 + lane];
        ax0 += bflo(a); ay0 += bfhi(a);
    }
    const float inv = 1.0f / (float)(d > 0 ? d : 1);
    const float sx = (((ax0 + ax1) + (ax2 + ax3)) + ((ax4 + ax5) + (ax6 + ax7))) * inv;
    const float sy = (((ay0 + ay1) + (ay2 + ay3)) + ((ay4 + ay5) + (ay6 + ay7))) * inv;
    const unsigned int o = (unsigned int)f2bf(sx) | ((unsigned int)f2bf(sy) << 16);
    reinterpret_cast<unsigned int*>(msgbf)[(size_t)node * 64 + lane] = o;
}

// -------- MFMA gemm: out = relu([hbf,msgbf] @ Wfrag + b) -------------------
template<bool OUT_BF16>
__global__ __launch_bounds__(256) void gemm_mfma(
    const unsigned short* __restrict__ hbf, const unsigned short* __restrict__ msgbf,
    const unsigned short* __restrict__ wfrag, const float* __restrict__ bias,
    float* __restrict__ outf, unsigned short* __restrict__ outbf, int n_nodes)
{
    __shared__ unsigned short sA[64 * 256];
    const int tid  = threadIdx.x;
    const int base = blockIdx.x * 64;

    #pragma unroll
    for (int it = 0; it < 8; ++it) {
        const int f  = it * 256 + tid;
        const int r  = f >> 5;
        const int cc = f & 31;
        const int node = base + r;
        short8 v = {0,0,0,0,0,0,0,0};
        if (node < n_nodes) {
            const unsigned short* sp = (cc < 16)
                ? hbf   + (size_t)node * D + cc * 8
                : msgbf + (size_t)node * D + (cc - 16) * 8;
            v = *reinterpret_cast<const short8*>(sp);
        }
        *reinterpret_cast<short8*>(&sA[r * 256 + ((cc ^ (r & 7)) * 8)]) = v;
    }
    __syncthreads();

    const int wv   = tid >> 6;
    const int lane = tid & 63;
    const int lrow = wv * 16 + (lane & 15);
    const int lgrp = lane >> 4;

    short8 a[8];
    #pragma unroll
    for (int kc = 0; kc < 8; ++kc) {
        const int chunk = kc * 4 + lgrp;
        a[kc] = *reinterpret_cast<const short8*>(
            &sA[lrow * 256 + ((chunk ^ (lrow & 7)) * 8)]);
    }

    const short8* wf = reinterpret_cast<const short8*>(wfrag);
    f32x4 acc[8];
    #pragma unroll
    for (int ct = 0; ct < 8; ++ct) {
        const float bb = bias[ct * 16 + (lane & 15)];
        acc[ct] = (f32x4){bb, bb, bb, bb};
    }
    #pragma unroll
    for (int ct = 0; ct < 8; ++ct) {
        #pragma unroll
        for (int kc = 0; kc < 8; ++kc) {
            const short8 b = wf[(ct * 8 + kc) * 64 + lane];
            acc[ct] = __builtin_amdgcn_mfma_f32_16x16x32_bf16(a[kc], b, acc[ct], 0, 0, 0);
        }
    }

    #pragma unroll
    for (int ct = 0; ct < 8; ++ct) {
        const int col = ct * 16 + (lane & 15);
        #pragma unroll
        for (int rg = 0; rg < 4; ++rg) {
            const int node = base + wv * 16 + lgrp * 4 + rg;
            if (node < n_nodes) {
                const float r = fmaxf(acc[ct][rg], 0.f);
                if (OUT_BF16) outbf[(size_t)node * D + col] = f2bf(r);
                else          outf [(size_t)node * D + col] = r;
            }
        }
    }
}

// ---------------------------------------------------------------------------
extern "C" void kernel_launch(void* const* d_in, const int* in_sizes, int n_in,
                              void* d_out, int out_size, void* d_ws, size_t ws_size,
                              hipStream_t stream)
{
    const float* h    = (const float*)d_in[0];
    const int*   esrc = (const int*)  d_in[1];
    const int*   edst = (const int*)  d_in[2];
    const float* W1   = (const float*)d_in[3];
    const float* b1   = (const float*)d_in[4];
    const float* W2   = (const float*)d_in[5];
    const float* b2   = (const float*)d_in[6];
    float* out = (float*)d_out;

    const int n_nodes = in_sizes[0] / D;
    const int n_edges = in_sizes[1];
    const int nbuck   = (n_nodes + BKT_NODES - 1) >> BKT_SHIFT;

    // workspace layout
    unsigned short* hbf   = (unsigned short*)d_ws;                 // [N][D]
    unsigned short* h1bf  = hbf  + (size_t)n_nodes * D;            // [N][D]
    unsigned short* msgbf = h1bf + (size_t)n_nodes * D;            // [N][D]
    unsigned short* wf1   = msgbf + (size_t)n_nodes * D;           // [32768]
    unsigned short* wf2   = wf1 + 32768;                           // [32768]
    int* adj_st           = (int*)(wf2 + 32768);                   // [nbuck*CAP]
    int* row_start        = adj_st + (size_t)nbuck * CAP;          // [N]
    int* deg              = row_start + n_nodes;                   // [N]
    int* cursor           = deg + n_nodes;                         // [NBK]

    const int nchunks = (n_edges + CHUNK - 1) / CHUNK;
    const int nodewave_blocks = (n_nodes + 3) / 4;
    const int gemm_blocks = (n_nodes + 63) / 64;
    const int n8 = n_nodes * D / 8;
    const int hblocks = (n8 + 255) / 256;

    // ---- precompute: conversions + single-pass bucketing (shared) ----
    (void)hipMemsetAsync(cursor, 0, NBK * sizeof(int), stream);
    prep_bucket<<<hblocks + 32 + nchunks, 256, 0, stream>>>(
        h, hbf, n8, hblocks, W1, W2, wf1, wf2, esrc, edst, cursor, adj_st, n_edges);
    bucket_fill<<<nbuck, 256, 0, stream>>>(cursor, adj_st, row_start, deg, n_nodes);

    // ---- layer 1: hbf -> h1bf (sorts rows in-flight, writes back) ----
    gather_sort<<<nodewave_blocks, 256, 0, stream>>>(hbf, adj_st, row_start, deg, msgbf, n_nodes);
    gemm_mfma<true><<<gemm_blocks, 256, 0, stream>>>(hbf, msgbf, wf1, b1, nullptr, h1bf, n_nodes);

    // ---- layer 2: h1bf -> out (f32) ----
    gather_kernel<<<nodewave_blocks, 256, 0, stream>>>(h1bf, adj_st, row_start, deg, msgbf, n_nodes);
    gemm_mfma<false><<<gemm_blocks, 256, 0, stream>>>(h1bf, msgbf, wf2, b2, out, nullptr, n_nodes);
}